// Round 5
// baseline (935.315 us; speedup 1.0000x reference)
//
#include <hip/hip_runtime.h>
#include <hip/hip_bf16.h>
#include <stdint.h>

// Problem constants (from reference): B=8,S=2048,IN=4096,OUT=4096,G=32
#define M_TOT 16384   // B*S
#define N_TOT 4096    // OUT
#define K_TOT 4096    // IN
#define NB    524288  // OUT*IN/G

// GEMM geometry: 256x256 tile, BK=64, 8 waves (2M x 4N). Round-5 = round-2
// schedule (best measured: 484us) with the MFMA shape switched to
// 32x32x16 bf16 (2382 TF ubench vs 2075 for 16x16x32 — 15% higher rate,
// the shape HK/AITER use). Staging/VMW/barrier structure is UNCHANGED.
#define BM 256
#define BN 256
#define BK 64
#define NT (K_TOT / BK)   // 64 K-tiles

typedef __attribute__((ext_vector_type(8))) __bf16 bf16x8;
typedef __attribute__((ext_vector_type(4))) float f32x4;
typedef __attribute__((ext_vector_type(16))) float f32x16;

#define BARF() do { asm volatile("" ::: "memory"); \
                    __builtin_amdgcn_s_barrier(); \
                    asm volatile("" ::: "memory"); } while (0)
#define VMW(n) asm volatile("s_waitcnt vmcnt(" #n ")" ::: "memory")

#define MFMA32(d, a, b) d = __builtin_amdgcn_mfma_f32_32x32x16_bf16(a, b, d, 0, 0, 0)
// One phase = one 32-row m-block x 2 n-blocks x 4 k-slices = 8 MFMA.
#define MFMA_PH(i, aR) do { \
  _Pragma("unroll") \
  for (int s_ = 0; s_ < 4; ++s_) { \
    MFMA32(acc[i][0], aR[s_], bF[0][s_]); \
    MFMA32(acc[i][1], aR[s_], bF[1][s_]); \
  } \
} while (0)

// ---------------------------------------------------------------------------
// Kernel 1: fused prep. Blocks [0,1024): dequant int4 W -> bf16 [OUT,IN].
// Blocks [1024,4096): cvt x f32 -> bf16. Both grid-stride.
// ---------------------------------------------------------------------------
#define DQ_BLOCKS 1024
#define CV_BLOCKS 3072
__global__ __launch_bounds__(256) void prep(
    const int* __restrict__ packed,          // [NB, 16] int32, one byte each
    const float* __restrict__ scale,         // [NB] f32 (promoted from fp16)
    const int* __restrict__ mask,            // [NB] int32 (promoted from bool)
    __hip_bfloat16* __restrict__ wout,       // [OUT*IN] bf16
    const float* __restrict__ x,
    __hip_bfloat16* __restrict__ xb)
{
    if (blockIdx.x < DQ_BLOCKS) {
        const size_t total = (size_t)NB * 4;
        for (size_t t = (size_t)blockIdx.x * blockDim.x + threadIdx.x;
             t < total; t += (size_t)DQ_BLOCKS * 256) {
            const int4 pk = ((const int4*)packed)[t];
            size_t nb = t >> 2;
            float se = scale[nb] * (mask[nb] ? 1.0f : 0.5f);
            int vals[4] = { pk.x, pk.y, pk.z, pk.w };
            __hip_bfloat16 o[8];
#pragma unroll
            for (int j = 0; j < 4; ++j) {
                int v = vals[j];
                o[2*j]   = __float2bfloat16((float)((v & 0xF) - 8) * se);
                o[2*j+1] = __float2bfloat16((float)(((v >> 4) & 0xF) - 8) * se);
            }
            int4 st;
            __builtin_memcpy(&st, o, 16);
            ((int4*)wout)[t] = st;
        }
    } else {
        const size_t total = (size_t)M_TOT * K_TOT / 8;
        const float4* xp = (const float4*)x;
        for (size_t t = (size_t)(blockIdx.x - DQ_BLOCKS) * blockDim.x + threadIdx.x;
             t < total; t += (size_t)CV_BLOCKS * 256) {
            float4 a = xp[2*t], b = xp[2*t + 1];
            __hip_bfloat16 o[8] = {
                __float2bfloat16(a.x), __float2bfloat16(a.y),
                __float2bfloat16(a.z), __float2bfloat16(a.w),
                __float2bfloat16(b.x), __float2bfloat16(b.y),
                __float2bfloat16(b.z), __float2bfloat16(b.w)
            };
            int4 st;
            __builtin_memcpy(&st, o, 16);
            ((int4*)xb)[t] = st;
        }
    }
}

// ---------------------------------------------------------------------------
// Kernel 3: C[M,N] = A[M,K] * W[N,K]^T + bias.  256x256, 8 waves, BK=64,
// 32x32x16 bf16 MFMA.  Per wave: 128x64 output = 4 m-blocks x 2 n-blocks
// of 32x32, acc = f32x16 acc[4][2] (128 AGPR, same as before).
//
// Schedule (= round-2's, race invariants unchanged):
//   p1: read B all (8 b128: 2 n-blk x 4 k-slices) + A-blk0 (4) + A-blk1 (4);
//       stage A(t+1); MFMA blk0; BARF
//   p2: read A-blk2 (ahead); stage B(t+2)H0; MFMA blk1; BARF
//   p3: read A-blk3 (ahead); stage B(t+2)H1; MFMA blk2; BARF
//   p4: MFMA blk3; VMW(4); BARF
// In-flight trace (steady, entry X = {B(t+1):4}): p1 +4 -> 8; p2 +2 -> 10;
//   p3 +2 -> 12; VMW(4) retires 8 oldest = B(t+1)+A(t+1) -> other buffer
//   fully resident; leaves {B(t+2):4}. ✓
// Stage-safety: staged region's last ds_reads drain before the barrier
//   preceding the stage (A region: blk3 read p3, gated at p4's MFMA, before
//   p4-end barrier, staged next-p1; B region: reads die at p1's MFMA-gate,
//   staged p2/p3 after p1-end barrier). ✓
// Fragment layout (32x32x16): A lane l holds row (l&31), k=(l>>5)*8+j ->
//   one b128 per (m-blk, k-slice): addr = (mblk_base + (l&31))*128 +
//   (((l>>5)*16 + s*32) ^ ((l&7)<<4)).  B symmetric on W rows.  Bank check:
//   per 16-lane quarter the XOR spreads 8 rows over 8 16B slots, each hit
//   2x -> 2-way = free (m136).
// C/D layout (m74/m101-verified): col = lane&31,
//   row = (r&3) + 8*(r>>2) + 4*(lane>>5), r in [0,16).
// ---------------------------------------------------------------------------
__global__ __launch_bounds__(512, 2) void gemm_bt(
    const __hip_bfloat16* __restrict__ A,   // [M_TOT, K_TOT] bf16
    const __hip_bfloat16* __restrict__ Bw,  // [N_TOT, K_TOT] bf16
    const float* __restrict__ bias,         // [N_TOT]
    float* __restrict__ C)                  // [M_TOT, N_TOT]
{
    __shared__ __align__(16) char lds[131072];

    const int tid  = threadIdx.x;
    const int lane = tid & 63;
    const int wave = tid >> 6;
    const int wm = wave >> 2;   // 0..1 -> rows wm*128 of the 256-row tile
    const int wn = wave & 3;    // 0..3 -> cols wn*64

    // T1: bijective XCD swizzle (nwg=1024, 1024%8==0), m-fast within XCD.
    const int wg = (blockIdx.x & 7) * 128 + (blockIdx.x >> 3);
    const int mt = wg & 63;
    const int nt = wg >> 6;
    const int m0 = mt * BM;
    const int n0 = nt * BN;

    // ---- staging addressing (per thread) ----
    // T2 swizzle: logical (row, byte-col cb) stored at cb ^ ((row&7)<<4).
    // global_load_lds dest is LINEAR; source col pre-swizzled (rule 21).
    const int srow = tid >> 3;                                   // 0..63
    const int scb  = ((tid & 7) * 16) ^ (((tid >> 3) & 7) << 4); // pre-swz src col
    const char* gA = (const char*)A  + ((size_t)(m0 + srow) * K_TOT) * 2 + scb;
    const char* gB = (const char*)Bw + ((size_t)(n0 + srow) * K_TOT) * 2 + scb;
    char* lA = (char*)lds + tid * 16;            // + p*65536 + region*8192
    char* lB = (char*)lds + 32768 + tid * 16;

    auto stA4 = [&](int t) {                     // stage full A tile (4 loads)
        if (t >= NT) t -= 2;                     // parity-preserving clamp
        const int p = t & 1;
        const size_t kb = (size_t)t * (BK * 2);
#pragma unroll
        for (int r = 0; r < 4; ++r) {
            __builtin_amdgcn_global_load_lds(
                (const __attribute__((address_space(1))) void*)
                    (gA + kb + (size_t)r * 64 * K_TOT * 2),
                (__attribute__((address_space(3))) void*)
                    (lA + p * 65536 + r * 8192), 16, 0, 0);
        }
    };
    auto stB2 = [&](int t, int h) {              // stage B half-tile (2 loads)
        if (t >= NT) t -= 2;
        const int p = t & 1;
        const size_t kb = (size_t)t * (BK * 2);
#pragma unroll
        for (int s = 0; s < 2; ++s) {
            const int r = 2 * h + s;
            __builtin_amdgcn_global_load_lds(
                (const __attribute__((address_space(1))) void*)
                    (gB + kb + (size_t)r * 64 * K_TOT * 2),
                (__attribute__((address_space(3))) void*)
                    (lB + p * 65536 + r * 8192), 16, 0, 0);
        }
    };

    // ---- fragment read addressing (32x32x16) ----
    const int swz = (lane & 7) << 4;
    int pcb[4];
#pragma unroll
    for (int s = 0; s < 4; ++s)
        pcb[s] = (((lane >> 5) * 16) + s * 32) ^ swz;
    int arow[4], brow[2];
#pragma unroll
    for (int i = 0; i < 4; ++i) arow[i] = (wm * 128 + i * 32 + (lane & 31)) * 128;
#pragma unroll
    for (int j = 0; j < 2; ++j) brow[j] = (wn * 64 + j * 32 + (lane & 31)) * 128;

    f32x16 acc[4][2] = {};

    const char* ldsA0 = (const char*)lds;
    const char* ldsB0 = (const char*)lds + 32768;
    const char* ldsA1 = (const char*)lds + 65536;
    const char* ldsB1 = (const char*)lds + 98304;

// One tile = 4 phases, 1 barrier each.  aCur/aNxt rotate (static idx, rule 20).
#define TILE_BLOCK(Ap, Bp, STG_A, STG_B0, STG_B1) do { \
    bf16x8 bF[2][4], aCur[4], aNxt[4]; \
    /* p1: read all B + A-blk0 + A-blk1; stage A(t+1); MFMA blk0 */ \
    _Pragma("unroll") \
    for (int j_ = 0; j_ < 2; ++j_) \
        _Pragma("unroll") \
        for (int s_ = 0; s_ < 4; ++s_) \
            bF[j_][s_] = *(const bf16x8*)((Bp) + brow[j_] + pcb[s_]); \
    _Pragma("unroll") \
    for (int s_ = 0; s_ < 4; ++s_) { \
        aCur[s_] = *(const bf16x8*)((Ap) + arow[0] + pcb[s_]); \
        aNxt[s_] = *(const bf16x8*)((Ap) + arow[1] + pcb[s_]); \
    } \
    STG_A; \
    __builtin_amdgcn_s_setprio(1); MFMA_PH(0, aCur); \
    __builtin_amdgcn_s_setprio(0); \
    BARF(); \
    /* p2: read A-blk2 (ahead); stage B(t+2)H0; MFMA blk1 */ \
    _Pragma("unroll") \
    for (int s_ = 0; s_ < 4; ++s_) \
        aCur[s_] = *(const bf16x8*)((Ap) + arow[2] + pcb[s_]); \
    STG_B0; \
    __builtin_amdgcn_s_setprio(1); MFMA_PH(1, aNxt); \
    __builtin_amdgcn_s_setprio(0); \
    BARF(); \
    /* p3: read A-blk3 (ahead); stage B(t+2)H1; MFMA blk2 */ \
    _Pragma("unroll") \
    for (int s_ = 0; s_ < 4; ++s_) \
        aNxt[s_] = *(const bf16x8*)((Ap) + arow[3] + pcb[s_]); \
    STG_B1; \
    __builtin_amdgcn_s_setprio(1); MFMA_PH(2, aCur); \
    __builtin_amdgcn_s_setprio(0); \
    BARF(); \
    /* p4: no reads/stages; MFMA blk3; counted vmcnt */ \
    __builtin_amdgcn_s_setprio(1); MFMA_PH(3, aNxt); \
    __builtin_amdgcn_s_setprio(0); \
    VMW(4); \
    BARF(); \
} while (0)

    // Prologue: B(T0) + A(T0) + B(T1) = 12 loads; vmcnt(4) completes T0's
    // 8 (B+A resident), leaves B(T1)'s 4 in flight -> steady-state pattern.
    stB2(0, 0); stB2(0, 1); stA4(0); stB2(1, 0); stB2(1, 1);
    VMW(4);
    BARF();

    for (int it = 0; it < NT / 2; ++it) {
        const int ta = 2 * it, tb = ta + 1;
        TILE_BLOCK(ldsA0, ldsB0, stA4(tb),     stB2(ta + 2, 0), stB2(ta + 2, 1));
        TILE_BLOCK(ldsA1, ldsB1, stA4(ta + 2), stB2(tb + 2, 0), stB2(tb + 2, 1));
    }
#undef TILE_BLOCK

    // Epilogue (32x32 C/D layout, m74/m101): col = lane&31,
    // row = (r&3) + 8*(r>>2) + 4*(lane>>5).
    const int cc  = lane & 31;
    const int hi4 = (lane >> 5) * 4;
#pragma unroll
    for (int j = 0; j < 2; ++j) {
        const int col = n0 + wn * 64 + j * 32 + cc;
        const float bv = bias[col];
#pragma unroll
        for (int i = 0; i < 4; ++i) {
            const size_t rbase = (size_t)(m0 + wm * 128 + i * 32 + hi4);
#pragma unroll
            for (int r = 0; r < 16; ++r) {
                const size_t row = rbase + (r & 3) + 8 * (r >> 2);
                C[row * N_TOT + col] = acc[i][j][r] + bv;
            }
        }
    }
    // Safety: drain LDS-DMA before endpgm so a successor block on this CU
    // can't see a stray late write into its freshly-allocated LDS.
    VMW(0);
}

// ---------------------------------------------------------------------------
extern "C" void kernel_launch(void* const* d_in, const int* in_sizes, int n_in,
                              void* d_out, int out_size, void* d_ws, size_t ws_size,
                              hipStream_t stream) {
    const float* x      = (const float*)d_in[0];
    const int*   wp     = (const int*)d_in[1];
    const float* wscale = (const float*)d_in[2];   // fp16 promoted to f32 by harness
    const int*   wmask  = (const int*)d_in[3];     // bool promoted to int32
    const float* bias   = (const float*)d_in[4];
    float*       out    = (float*)d_out;

    // Workspace: W bf16 (32 MB) at offset 0, x bf16 (128 MB) after.
    __hip_bfloat16* Wb = (__hip_bfloat16*)d_ws;
    __hip_bfloat16* Xb = (__hip_bfloat16*)((char*)d_ws + (size_t)N_TOT * K_TOT * 2);

    // 1) fused dequant W + convert x (one dispatch, both grid-stride)
    prep<<<DQ_BLOCKS + CV_BLOCKS, 256, 0, stream>>>(wp, wscale, wmask, Wb, x, Xb);
    // 2) GEMM: 64 x 16 tiles of 256x256, 512 threads (8 waves)
    gemm_bt<<<(M_TOT / BM) * (N_TOT / BN), 512, 0, stream>>>(Xb, Wb, bias, out);
}